// Round 10
// baseline (152.507 us; speedup 1.0000x reference)
//
#include <hip/hip_runtime.h>
#include <hip/hip_bf16.h>
#include <math.h>

#define TOKENS 8192
#define D_REAL 768
#define D_HID  512
#define D_MODEL 4096

typedef __attribute__((ext_vector_type(8))) short bf16x8;   // 8 bf16 in 4 VGPRs
typedef __attribute__((ext_vector_type(4))) float f32x4;    // MFMA accumulator

// fp32 -> bf16, round-to-nearest-even
__device__ inline unsigned short f2bf(float f) {
    union { float f; unsigned u; } v; v.f = f;
    unsigned r = v.u + 0x7FFFu + ((v.u >> 16) & 1u);
    return (unsigned short)(r >> 16);
}
__device__ inline float bf2f(unsigned short h) {
    union { unsigned u; float f; } v; v.u = ((unsigned)h) << 16;
    return v.f;
}
__device__ inline bf16x8 cvt8(float4 a, float4 b) {
    bf16x8 r;
    r[0] = (short)f2bf(a.x); r[1] = (short)f2bf(a.y);
    r[2] = (short)f2bf(a.z); r[3] = (short)f2bf(a.w);
    r[4] = (short)f2bf(b.x); r[5] = (short)f2bf(b.y);
    r[6] = (short)f2bf(b.z); r[7] = (short)f2bf(b.w);
    return r;
}

// async global->LDS, 16B per lane. LDS dest = wave-uniform base + lane*16.
__device__ inline void gload_lds16(const void* g, void* lds_wave_base) {
    __builtin_amdgcn_global_load_lds(
        (const __attribute__((address_space(1))) unsigned*)g,
        (__attribute__((address_space(3))) unsigned*)lds_wave_base,
        16, 0, 0);
}

// ---------------------------------------------------------------------------
// GEMM1 (+fused gather, round-9 form): Hb = bf16(real[ids]) * w1b^T, bf16 out.
// Tile 64x128, BK=32, 4 waves (2x2). Grid (128,4) = 512 blocks.
// ---------------------------------------------------------------------------
__global__ __launch_bounds__(256)
void gemm1_mfma(const float* __restrict__ real, const int* __restrict__ ids,
                const unsigned short* __restrict__ B,
                unsigned short* __restrict__ C)
{
    constexpr int K = D_REAL, N = D_HID;
    __shared__ __align__(16) unsigned short As[64 * 32];    // 4 KB
    __shared__ __align__(16) unsigned short Bs[128 * 32];   // 8 KB
    __shared__ int sIds[64];

    const int tid = threadIdx.x;
    const int rowBase = blockIdx.x * 64;
    const int colBase = blockIdx.y * 128;

    if (tid < 64) sIds[tid] = ids[rowBase + tid];
    __syncthreads();

    const int srow = tid >> 2;           // 0..63
    const int scol = (tid & 3) * 8;      // k offset
    const float* gA = real + (size_t)sIds[srow] * K + scol;
    const unsigned short* gB = B + (size_t)(colBase + srow) * K + scol;
    unsigned short* lB = Bs + (tid >> 6) * 512;

    const int lane = tid & 63;
    const int wv   = tid >> 6;
    const int wm   = (wv >> 1) * 32;
    const int wn   = (wv & 1) * 64;
    const int frow = lane & 15;
    const int fk   = (lane >> 4) * 8;

    f32x4 acc[2][4];
    #pragma unroll
    for (int i = 0; i < 2; i++)
        #pragma unroll
        for (int j = 0; j < 4; j++) acc[i][j] = (f32x4)0.f;

    for (int k0 = 0; k0 < K; k0 += 32) {
        gload_lds16(gB + k0,                lB);
        gload_lds16(gB + k0 + (size_t)64*K, lB + 2048);
        const float4 a0 = *reinterpret_cast<const float4*>(gA + k0);
        const float4 a1 = *reinterpret_cast<const float4*>(gA + k0 + 4);
        *reinterpret_cast<bf16x8*>(&As[srow * 32 + scol]) = cvt8(a0, a1);
        __syncthreads();   // drains gloads + ds_write + a-loads

        bf16x8 af[2], bg[4];
        #pragma unroll
        for (int i = 0; i < 2; i++)
            af[i] = *reinterpret_cast<const bf16x8*>(&As[(wm + i*16 + frow) * 32 + fk]);
        #pragma unroll
        for (int j = 0; j < 4; j++)
            bg[j] = *reinterpret_cast<const bf16x8*>(&Bs[(wn + j*16 + frow) * 32 + fk]);

        #pragma unroll
        for (int i = 0; i < 2; i++)
            #pragma unroll
            for (int j = 0; j < 4; j++)
                acc[i][j] = __builtin_amdgcn_mfma_f32_16x16x32_bf16(af[i], bg[j], acc[i][j], 0, 0, 0);
        __syncthreads();
    }

    const int orow0 = wm + (lane >> 4) * 4;
    const int ocol0 = wn + frow;
    #pragma unroll
    for (int i = 0; i < 2; i++)
        #pragma unroll
        for (int r = 0; r < 4; r++) {
            unsigned short* dst = C + (size_t)(rowBase + orow0 + i*16 + r) * N + colBase + ocol0;
            #pragma unroll
            for (int j = 0; j < 4; j++)
                dst[j * 16] = f2bf(acc[i][j][r]);
        }
}

// ---------------------------------------------------------------------------
// GEMM2, N-loop streaming form: out = Hb * w2b^T + embed[ids], fp32 out.
// Grid 256 = 1 block/CU (no tail). Block = 64 rows x 2048 cols (half of N),
// 512 thr = 8 waves (2M x 4N), wave = 32r x 32c per col-tile (2mf x 2nf).
// A panel [64][512] bf16 staged to LDS ONCE (64 KB, XOR-swizzled).
// Loop 16 col-tiles x 8 K-steps; B [128][64] double-buffered (2x16 KB),
// staged 1-ahead before compute; ONE __syncthreads per K-step.
// Per col-tile epilogue (embed gather-add + store) runs inline -> HBM
// traffic streams across the whole kernel, overlapped with MFMA.
// ---------------------------------------------------------------------------
__global__ __launch_bounds__(512, 1)
void gemm2_nloop(const unsigned short* __restrict__ A,
                 const unsigned short* __restrict__ B,
                 const int* __restrict__ ids,
                 const float* __restrict__ embed,
                 float* __restrict__ C)
{
    constexpr int K = D_HID, N = D_MODEL, NCT = 16, NGT = NCT * 8;  // 128 B-tiles
    __shared__ __align__(16) unsigned short Al[64 * 512];     // 64 KB
    __shared__ __align__(16) unsigned short Bl[2][128 * 64];  // 2 x 16 KB
    __shared__ int sIds[64];

    // grid 256: xcd = f&7 -> col-half (w2b half stays L2-resident per XCD);
    // (xcd>>1, j) -> M-tile. Bijective.
    const int f   = blockIdx.x;
    const int xcd = f & 7;
    const int j   = f >> 3;                       // 0..31
    const int rowBase = ((xcd >> 1) * 32 + j) * 64;
    const int colHalf = (xcd & 1) * 2048;

    const int tid  = threadIdx.x;
    const int lane = tid & 63;
    const int wv   = tid >> 6;     // 0..7
    const int wr   = wv >> 2;      // 0..1  (32-row half)
    const int wc   = wv & 3;       // 0..3  (32-col quarter)
    const int frow = lane & 15;
    const int fq   = lane >> 4;    // 0..3

    if (tid < 64) sIds[tid] = ids[rowBase + tid];

    // ---- stage A once: [64 rows][64 slots of 16B], slot^row&7 swizzle
    #pragma unroll
    for (int rr = 0; rr < 8; ++rr) {
        const int c   = rr * 512 + tid;     // 0..4095
        const int row = c >> 6;             // 0..63
        const int ls  = c & 63;             // local slot
        const int gs  = (ls & 56) | ((ls ^ row) & 7);
        gload_lds16(A + (size_t)(rowBase + row) * K + gs * 8,
                    &Al[(rr * 512 + wv * 64) * 8]);
    }

    // B tile gt = ct*8+kt -> buf gt&1, [128 rows][8 slots], slot^row&7 swizzle
    auto STAGEB = [&](int gt) {
        if (gt >= NGT) return;
        const int ct = gt >> 3, kt = gt & 7;
        unsigned short* Bb = Bl[gt & 1];
        #pragma unroll
        for (int u = 0; u < 2; ++u) {
            const int c   = u * 512 + tid;  // 0..1023
            const int row = c >> 3;         // 0..127
            const int gs  = ((c & 7) ^ row) & 7;
            gload_lds16(B + (size_t)(colHalf + ct * 128 + row) * K + kt * 64 + gs * 8,
                        Bb + (u * 512 + wv * 64) * 8);
        }
    };

    STAGEB(0);
    __syncthreads();   // A + B(0) staged and drained

    for (int ct = 0; ct < NCT; ++ct) {
        f32x4 acc[2][2];
        #pragma unroll
        for (int i = 0; i < 2; i++)
            #pragma unroll
            for (int n = 0; n < 2; n++) acc[i][n] = (f32x4)0.f;

        #pragma unroll
        for (int kt = 0; kt < 8; ++kt) {
            const int gt = ct * 8 + kt;
            const unsigned short* Bb = Bl[gt & 1];
            bf16x8 af[2][2], bg[2][2];
            #pragma unroll
            for (int mf = 0; mf < 2; ++mf)
                #pragma unroll
                for (int kk = 0; kk < 2; ++kk) {
                    const int arow = wr * 32 + mf * 16 + frow;
                    const int s = kt * 8 + ((kk * 4 + fq) ^ (arow & 7));
                    af[mf][kk] = *reinterpret_cast<const bf16x8*>(&Al[arow * 512 + s * 8]);
                }
            #pragma unroll
            for (int nf = 0; nf < 2; ++nf)
                #pragma unroll
                for (int kk = 0; kk < 2; ++kk) {
                    const int brow = wc * 32 + nf * 16 + frow;
                    const int s = (kk * 4 + fq) ^ (brow & 7);
                    bg[nf][kk] = *reinterpret_cast<const bf16x8*>(&Bb[brow * 64 + s * 8]);
                }
            STAGEB(gt + 1);   // -> buf^1; its last reads finished before prev barrier

            #pragma unroll
            for (int mf = 0; mf < 2; ++mf)
                #pragma unroll
                for (int nf = 0; nf < 2; ++nf)
                    #pragma unroll
                    for (int kk = 0; kk < 2; ++kk)
                        acc[mf][nf] = __builtin_amdgcn_mfma_f32_16x16x32_bf16(
                            af[mf][kk], bg[nf][kk], acc[mf][nf], 0, 0, 0);

            if (kt == 7) {
                // inline epilogue for col-tile ct (acc complete)
                const int ocol = colHalf + ct * 128 + wc * 32 + frow;
                #pragma unroll
                for (int mf = 0; mf < 2; ++mf) {
                    #pragma unroll
                    for (int r = 0; r < 4; ++r) {
                        const int lrow = wr * 32 + mf * 16 + fq * 4 + r;
                        const float* e = embed + (size_t)sIds[lrow] * N + ocol;
                        float* o = C + (size_t)(rowBase + lrow) * N + ocol;
                        #pragma unroll
                        for (int nf = 0; nf < 2; ++nf)
                            o[nf * 16] = acc[mf][nf][r] + e[nf * 16];
                    }
                }
            }
            __syncthreads();   // drains STAGEB(gt+1) (+epilogue ops each 8th step)
        }
    }
}

// ---------------------------------------------------------------------------
// fp32 -> bf16 bulk convert of w1 and w2 in one launch
// ---------------------------------------------------------------------------
__global__ __launch_bounds__(256)
void convert2_bf16(const float* __restrict__ s1, unsigned short* __restrict__ d1, int n1,
                   const float* __restrict__ s2, unsigned short* __restrict__ d2, int n2)
{
    int i = blockIdx.x * 256 + threadIdx.x;
    const float* src; unsigned short* dst;
    if (i < n1) { src = s1; dst = d1; }
    else {
        i -= n1;
        if (i >= n2) return;
        src = s2; dst = d2;
    }
    const float4 v = reinterpret_cast<const float4*>(src)[i];
    ushort4 o;
    o.x = f2bf(v.x); o.y = f2bf(v.y); o.z = f2bf(v.z); o.w = f2bf(v.w);
    reinterpret_cast<ushort4*>(dst)[i] = o;
}

// ---------------------------------------------------------------------------
// In-place LayerNorm + ELU on bf16 H [TOKENS][512]. One wave per row.
// ---------------------------------------------------------------------------
__global__ __launch_bounds__(256)
void ln_elu_bf16(unsigned short* __restrict__ H,
                 const float* __restrict__ ln_w, const float* __restrict__ ln_b)
{
    const int row = blockIdx.x * 4 + (threadIdx.x >> 6);
    const int t = threadIdx.x & 63;
    unsigned short* x = H + (size_t)row * D_HID + t * 8;

    bf16x8 v = *reinterpret_cast<const bf16x8*>(x);
    float fv[8], s = 0.f, ss = 0.f;
    #pragma unroll
    for (int j = 0; j < 8; j++) {
        fv[j] = bf2f((unsigned short)v[j]);
        s += fv[j]; ss += fv[j] * fv[j];
    }
    #pragma unroll
    for (int off = 32; off > 0; off >>= 1) {
        s  += __shfl_down(s, off);
        ss += __shfl_down(ss, off);
    }
    s = __shfl(s, 0); ss = __shfl(ss, 0);
    const float mu = s * (1.f / D_HID);
    const float var = ss * (1.f / D_HID) - mu * mu;
    const float rstd = rsqrtf(var + 1e-5f);

    const float4 w0 = *reinterpret_cast<const float4*>(ln_w + t * 8);
    const float4 w1 = *reinterpret_cast<const float4*>(ln_w + t * 8 + 4);
    const float4 b0 = *reinterpret_cast<const float4*>(ln_b + t * 8);
    const float4 b1 = *reinterpret_cast<const float4*>(ln_b + t * 8 + 4);
    const float wa[8] = { w0.x, w0.y, w0.z, w0.w, w1.x, w1.y, w1.z, w1.w };
    const float ba[8] = { b0.x, b0.y, b0.z, b0.w, b1.x, b1.y, b1.z, b1.w };

    bf16x8 o;
    #pragma unroll
    for (int j = 0; j < 8; j++) {
        float y = (fv[j] - mu) * rstd * wa[j] + ba[j];
        y = y > 0.f ? y : expm1f(y);
        o[j] = (short)f2bf(y);
    }
    *reinterpret_cast<bf16x8*>(x) = o;
}

extern "C" void kernel_launch(void* const* d_in, const int* in_sizes, int n_in,
                              void* d_out, int out_size, void* d_ws, size_t ws_size,
                              hipStream_t stream)
{
    const float* real  = (const float*)d_in[0];   // [32000, 768]
    const float* embed = (const float*)d_in[1];   // [32000, 4096]
    const float* w1    = (const float*)d_in[2];   // [512, 768]
    const float* w2    = (const float*)d_in[3];   // [4096, 512]
    const float* ln_w  = (const float*)d_in[4];   // [512]
    const float* ln_b  = (const float*)d_in[5];   // [512]
    const int*   ids   = (const int*)d_in[6];     // [8192]
    float* out = (float*)d_out;                   // [8192, 4096] fp32

    unsigned short* Hb  = (unsigned short*)d_ws;             // [8192][512] bf16
    unsigned short* w1b = Hb  + (size_t)TOKENS * D_HID;      // [512][768]  bf16
    unsigned short* w2b = w1b + (size_t)D_HID * D_REAL;      // [4096][512] bf16

    const int n1 = D_HID * D_REAL / 4, n2 = D_MODEL * D_HID / 4;
    convert2_bf16<<<(n1 + n2 + 255) / 256, 256, 0, stream>>>(w1, w1b, n1, w2, w2b, n2);

    dim3 g1(TOKENS / 64, D_HID / 128);
    gemm1_mfma<<<g1, 256, 0, stream>>>(real, ids, w1b, Hb);

    ln_elu_bf16<<<TOKENS / 4, 256, 0, stream>>>(Hb, ln_w, ln_b);

    gemm2_nloop<<<256, 512, 0, stream>>>(Hb, w2b, ids, embed, out);
}

// Round 11
// 134.069 us; speedup vs baseline: 1.1375x; 1.1375x over previous
//
#include <hip/hip_runtime.h>
#include <hip/hip_bf16.h>
#include <math.h>

#define TOKENS 8192
#define D_REAL 768
#define D_HID  512
#define D_MODEL 4096

typedef __attribute__((ext_vector_type(8))) short bf16x8;   // 8 bf16 in 4 VGPRs
typedef __attribute__((ext_vector_type(4))) float f32x4;    // MFMA accumulator

// fp32 -> bf16, round-to-nearest-even
__device__ inline unsigned short f2bf(float f) {
    union { float f; unsigned u; } v; v.f = f;
    unsigned r = v.u + 0x7FFFu + ((v.u >> 16) & 1u);
    return (unsigned short)(r >> 16);
}
__device__ inline float bf2f(unsigned short h) {
    union { unsigned u; float f; } v; v.u = ((unsigned)h) << 16;
    return v.f;
}
__device__ inline bf16x8 cvt8(float4 a, float4 b) {
    bf16x8 r;
    r[0] = (short)f2bf(a.x); r[1] = (short)f2bf(a.y);
    r[2] = (short)f2bf(a.z); r[3] = (short)f2bf(a.w);
    r[4] = (short)f2bf(b.x); r[5] = (short)f2bf(b.y);
    r[6] = (short)f2bf(b.z); r[7] = (short)f2bf(b.w);
    return r;
}

// async global->LDS, 16B per lane. LDS dest = wave-uniform base + lane*16.
__device__ inline void gload_lds16(const void* g, void* lds_wave_base) {
    __builtin_amdgcn_global_load_lds(
        (const __attribute__((address_space(1))) unsigned*)g,
        (__attribute__((address_space(3))) unsigned*)lds_wave_base,
        16, 0, 0);
}

// ---------------------------------------------------------------------------
// GEMM1 (+fused gather, round-9 form): Hb = bf16(real[ids]) * w1b^T, bf16 out.
// Tile 64x128, BK=32, 4 waves (2x2). Grid (128,4) = 512 blocks.
// ---------------------------------------------------------------------------
__global__ __launch_bounds__(256)
void gemm1_mfma(const float* __restrict__ real, const int* __restrict__ ids,
                const unsigned short* __restrict__ B,
                unsigned short* __restrict__ C)
{
    constexpr int K = D_REAL, N = D_HID;
    __shared__ __align__(16) unsigned short As[64 * 32];    // 4 KB
    __shared__ __align__(16) unsigned short Bs[128 * 32];   // 8 KB
    __shared__ int sIds[64];

    const int tid = threadIdx.x;
    const int rowBase = blockIdx.x * 64;
    const int colBase = blockIdx.y * 128;

    if (tid < 64) sIds[tid] = ids[rowBase + tid];
    __syncthreads();

    const int srow = tid >> 2;           // 0..63
    const int scol = (tid & 3) * 8;      // k offset
    const float* gA = real + (size_t)sIds[srow] * K + scol;
    const unsigned short* gB = B + (size_t)(colBase + srow) * K + scol;
    unsigned short* lB = Bs + (tid >> 6) * 512;

    const int lane = tid & 63;
    const int wv   = tid >> 6;
    const int wm   = (wv >> 1) * 32;
    const int wn   = (wv & 1) * 64;
    const int frow = lane & 15;
    const int fk   = (lane >> 4) * 8;

    f32x4 acc[2][4];
    #pragma unroll
    for (int i = 0; i < 2; i++)
        #pragma unroll
        for (int j = 0; j < 4; j++) acc[i][j] = (f32x4)0.f;

    for (int k0 = 0; k0 < K; k0 += 32) {
        gload_lds16(gB + k0,                lB);
        gload_lds16(gB + k0 + (size_t)64*K, lB + 2048);
        const float4 a0 = *reinterpret_cast<const float4*>(gA + k0);
        const float4 a1 = *reinterpret_cast<const float4*>(gA + k0 + 4);
        *reinterpret_cast<bf16x8*>(&As[srow * 32 + scol]) = cvt8(a0, a1);
        __syncthreads();   // drains gloads + ds_write + a-loads

        bf16x8 af[2], bg[4];
        #pragma unroll
        for (int i = 0; i < 2; i++)
            af[i] = *reinterpret_cast<const bf16x8*>(&As[(wm + i*16 + frow) * 32 + fk]);
        #pragma unroll
        for (int j = 0; j < 4; j++)
            bg[j] = *reinterpret_cast<const bf16x8*>(&Bs[(wn + j*16 + frow) * 32 + fk]);

        #pragma unroll
        for (int i = 0; i < 2; i++)
            #pragma unroll
            for (int j = 0; j < 4; j++)
                acc[i][j] = __builtin_amdgcn_mfma_f32_16x16x32_bf16(af[i], bg[j], acc[i][j], 0, 0, 0);
        __syncthreads();
    }

    const int orow0 = wm + (lane >> 4) * 4;
    const int ocol0 = wn + frow;
    #pragma unroll
    for (int i = 0; i < 2; i++)
        #pragma unroll
        for (int r = 0; r < 4; r++) {
            unsigned short* dst = C + (size_t)(rowBase + orow0 + i*16 + r) * N + colBase + ocol0;
            #pragma unroll
            for (int j = 0; j < 4; j++)
                dst[j * 16] = f2bf(acc[i][j][r]);
        }
}

// ---------------------------------------------------------------------------
// GEMM2: out[8192][4096] = Hb * w2b^T + embed[ids], fp32 out.
// 256x128 tile, BK=32, 256 thr = 4 waves (2Mx2N), wave = 128x64 = 8x4 frags.
// Single-buffer 2-barrier K-loop (proven round-6 schedule). Grid 1024 blocks,
// ~2 resident blocks/CU -> 2 GENERATIONS: gen-2 K-loops (MFMA) overlap
// gen-1 epilogues (268 MB embed+out HBM stream) instead of the whole grid
// hitting the epilogue burst in lockstep. XCD-slab swizzle (bijective).
// ---------------------------------------------------------------------------
__global__ __launch_bounds__(256, 2)
void gemm2_mfma(const unsigned short* __restrict__ A,
                const unsigned short* __restrict__ B,
                const int* __restrict__ ids,
                const float* __restrict__ embed,
                float* __restrict__ C)
{
    constexpr int K = D_HID, N = D_MODEL;
    __shared__ __align__(16) unsigned short As[256 * 32];   // 16 KB
    __shared__ __align__(16) unsigned short Bs[128 * 32];   // 8 KB
    __shared__ int sIds[256];

    // bijective swizzle: 32 row-tiles x 32 col-tiles; xcd owns 4 row-tiles
    const int f   = blockIdx.x;          // 0..1023
    const int xcd = f & 7;
    const int idx = f >> 3;              // 0..127
    const int rowBase = (xcd * 4 + (idx & 3)) * 256;
    const int colBase = (idx >> 2) * 128;

    const int tid = threadIdx.x;
    sIds[tid] = ids[rowBase + tid];      // 256 threads cover all 256 rows

    // staging: thread t loads 16B at row chunks {0,64,128,192} (A) / {0,64} (B)
    const int srow = tid >> 2;           // 0..63
    const int scol = (tid & 3) * 8;
    const unsigned short* gA = A + (size_t)(rowBase + srow) * K + scol;
    const unsigned short* gB = B + (size_t)(colBase + srow) * K + scol;
    unsigned short* lA = As + (tid >> 6) * 512;   // wave-uniform base
    unsigned short* lB = Bs + (tid >> 6) * 512;

    const int lane = tid & 63;
    const int wv   = tid >> 6;
    const int wm   = (wv >> 1) * 128;    // wave row offset (2 waves in M)
    const int wn   = (wv & 1) * 64;      // wave col offset (2 waves in N)
    const int frow = lane & 15;
    const int fq   = lane >> 4;          // 0..3
    const int fk   = fq * 8;

    f32x4 acc[8][4];
    #pragma unroll
    for (int i = 0; i < 8; i++)
        #pragma unroll
        for (int j = 0; j < 4; j++) acc[i][j] = (f32x4)0.f;

    for (int k0 = 0; k0 < K; k0 += 32) {
        gload_lds16(gA,                 lA);
        gload_lds16(gA + (size_t)64*K,  lA + 2048);
        gload_lds16(gA + (size_t)128*K, lA + 4096);
        gload_lds16(gA + (size_t)192*K, lA + 6144);
        gload_lds16(gB,                 lB);
        gload_lds16(gB + (size_t)64*K,  lB + 2048);
        gA += 32; gB += 32;
        __syncthreads();   // implicit vmcnt(0): tiles staged

        bf16x8 af[8], bg[4];
        #pragma unroll
        for (int mf = 0; mf < 8; mf++)
            af[mf] = *reinterpret_cast<const bf16x8*>(&As[(wm + mf*16 + frow) * 32 + fk]);
        #pragma unroll
        for (int nf = 0; nf < 4; nf++)
            bg[nf] = *reinterpret_cast<const bf16x8*>(&Bs[(wn + nf*16 + frow) * 32 + fk]);

        #pragma unroll
        for (int mf = 0; mf < 8; mf++)
            #pragma unroll
            for (int nf = 0; nf < 4; nf++)
                acc[mf][nf] = __builtin_amdgcn_mfma_f32_16x16x32_bf16(
                    af[mf], bg[nf], acc[mf][nf], 0, 0, 0);
        __syncthreads();
    }

    // epilogue: embed gather-add + fp32 stores (C/D: row=fq*4+r, col=frow)
    const int ocol0 = colBase + wn + frow;
    #pragma unroll
    for (int mf = 0; mf < 8; mf++) {
        #pragma unroll
        for (int r = 0; r < 4; r++) {
            const int lrow = wm + mf * 16 + fq * 4 + r;
            const float* e = embed + (size_t)sIds[lrow] * N + ocol0;
            float* o = C + (size_t)(rowBase + lrow) * N + ocol0;
            #pragma unroll
            for (int nf = 0; nf < 4; nf++)
                o[nf * 16] = acc[mf][nf][r] + e[nf * 16];
        }
    }
}

// ---------------------------------------------------------------------------
// fp32 -> bf16 bulk convert of w1 and w2 in one launch
// ---------------------------------------------------------------------------
__global__ __launch_bounds__(256)
void convert2_bf16(const float* __restrict__ s1, unsigned short* __restrict__ d1, int n1,
                   const float* __restrict__ s2, unsigned short* __restrict__ d2, int n2)
{
    int i = blockIdx.x * 256 + threadIdx.x;
    const float* src; unsigned short* dst;
    if (i < n1) { src = s1; dst = d1; }
    else {
        i -= n1;
        if (i >= n2) return;
        src = s2; dst = d2;
    }
    const float4 v = reinterpret_cast<const float4*>(src)[i];
    ushort4 o;
    o.x = f2bf(v.x); o.y = f2bf(v.y); o.z = f2bf(v.z); o.w = f2bf(v.w);
    reinterpret_cast<ushort4*>(dst)[i] = o;
}

// ---------------------------------------------------------------------------
// In-place LayerNorm + ELU on bf16 H [TOKENS][512]. One wave per row.
// ---------------------------------------------------------------------------
__global__ __launch_bounds__(256)
void ln_elu_bf16(unsigned short* __restrict__ H,
                 const float* __restrict__ ln_w, const float* __restrict__ ln_b)
{
    const int row = blockIdx.x * 4 + (threadIdx.x >> 6);
    const int t = threadIdx.x & 63;
    unsigned short* x = H + (size_t)row * D_HID + t * 8;

    bf16x8 v = *reinterpret_cast<const bf16x8*>(x);
    float fv[8], s = 0.f, ss = 0.f;
    #pragma unroll
    for (int j = 0; j < 8; j++) {
        fv[j] = bf2f((unsigned short)v[j]);
        s += fv[j]; ss += fv[j] * fv[j];
    }
    #pragma unroll
    for (int off = 32; off > 0; off >>= 1) {
        s  += __shfl_down(s, off);
        ss += __shfl_down(ss, off);
    }
    s = __shfl(s, 0); ss = __shfl(ss, 0);
    const float mu = s * (1.f / D_HID);
    const float var = ss * (1.f / D_HID) - mu * mu;
    const float rstd = rsqrtf(var + 1e-5f);

    const float4 w0 = *reinterpret_cast<const float4*>(ln_w + t * 8);
    const float4 w1 = *reinterpret_cast<const float4*>(ln_w + t * 8 + 4);
    const float4 b0 = *reinterpret_cast<const float4*>(ln_b + t * 8);
    const float4 b1 = *reinterpret_cast<const float4*>(ln_b + t * 8 + 4);
    const float wa[8] = { w0.x, w0.y, w0.z, w0.w, w1.x, w1.y, w1.z, w1.w };
    const float ba[8] = { b0.x, b0.y, b0.z, b0.w, b1.x, b1.y, b1.z, b1.w };

    bf16x8 o;
    #pragma unroll
    for (int j = 0; j < 8; j++) {
        float y = (fv[j] - mu) * rstd * wa[j] + ba[j];
        y = y > 0.f ? y : expm1f(y);
        o[j] = (short)f2bf(y);
    }
    *reinterpret_cast<bf16x8*>(x) = o;
}

extern "C" void kernel_launch(void* const* d_in, const int* in_sizes, int n_in,
                              void* d_out, int out_size, void* d_ws, size_t ws_size,
                              hipStream_t stream)
{
    const float* real  = (const float*)d_in[0];   // [32000, 768]
    const float* embed = (const float*)d_in[1];   // [32000, 4096]
    const float* w1    = (const float*)d_in[2];   // [512, 768]
    const float* w2    = (const float*)d_in[3];   // [4096, 512]
    const float* ln_w  = (const float*)d_in[4];   // [512]
    const float* ln_b  = (const float*)d_in[5];   // [512]
    const int*   ids   = (const int*)d_in[6];     // [8192]
    float* out = (float*)d_out;                   // [8192, 4096] fp32

    unsigned short* Hb  = (unsigned short*)d_ws;             // [8192][512] bf16
    unsigned short* w1b = Hb  + (size_t)TOKENS * D_HID;      // [512][768]  bf16
    unsigned short* w2b = w1b + (size_t)D_HID * D_REAL;      // [4096][512] bf16

    const int n1 = D_HID * D_REAL / 4, n2 = D_MODEL * D_HID / 4;
    convert2_bf16<<<(n1 + n2 + 255) / 256, 256, 0, stream>>>(w1, w1b, n1, w2, w2b, n2);

    dim3 g1(TOKENS / 64, D_HID / 128);
    gemm1_mfma<<<g1, 256, 0, stream>>>(real, ids, w1b, Hb);

    ln_elu_bf16<<<TOKENS / 4, 256, 0, stream>>>(Hb, ln_w, ln_b);

    gemm2_mfma<<<1024, 256, 0, stream>>>(Hb, w2b, ids, embed, out);
}

// Round 12
// 124.946 us; speedup vs baseline: 1.2206x; 1.0730x over previous
//
#include <hip/hip_runtime.h>
#include <hip/hip_bf16.h>
#include <math.h>

#define TOKENS 8192
#define D_REAL 768
#define D_HID  512
#define D_MODEL 4096

typedef __attribute__((ext_vector_type(8))) short bf16x8;   // 8 bf16 in 4 VGPRs
typedef __attribute__((ext_vector_type(4))) float f32x4;    // MFMA accumulator

// fp32 -> bf16, round-to-nearest-even
__device__ inline unsigned short f2bf(float f) {
    union { float f; unsigned u; } v; v.f = f;
    unsigned r = v.u + 0x7FFFu + ((v.u >> 16) & 1u);
    return (unsigned short)(r >> 16);
}
__device__ inline float bf2f(unsigned short h) {
    union { unsigned u; float f; } v; v.u = ((unsigned)h) << 16;
    return v.f;
}
__device__ inline bf16x8 cvt8(float4 a, float4 b) {
    bf16x8 r;
    r[0] = (short)f2bf(a.x); r[1] = (short)f2bf(a.y);
    r[2] = (short)f2bf(a.z); r[3] = (short)f2bf(a.w);
    r[4] = (short)f2bf(b.x); r[5] = (short)f2bf(b.y);
    r[6] = (short)f2bf(b.z); r[7] = (short)f2bf(b.w);
    return r;
}

// async global->LDS, 16B per lane. LDS dest = wave-uniform base + lane*16.
__device__ inline void gload_lds16(const void* g, void* lds_wave_base) {
    __builtin_amdgcn_global_load_lds(
        (const __attribute__((address_space(1))) unsigned*)g,
        (__attribute__((address_space(3))) unsigned*)lds_wave_base,
        16, 0, 0);
}

// compiler-fence + hw barrier (no implicit waitcnt drain, unlike __syncthreads)
__device__ inline void BAR() {
    asm volatile("" ::: "memory");
    __builtin_amdgcn_s_barrier();
    asm volatile("" ::: "memory");
}

// ---------------------------------------------------------------------------
// GEMM1 (+fused gather): Hb = bf16(real[ids]) * w1b^T, bf16 out.
// Tile 64x128, BK=32, 4 waves (2x2). A reg-staged from fp32 real rows
// (float4 x2 -> cvt -> ds_write_b128); B via global_load_lds from w1b.
// Grid (128,4) = 512 blocks.
// ---------------------------------------------------------------------------
__global__ __launch_bounds__(256)
void gemm1_mfma(const float* __restrict__ real, const int* __restrict__ ids,
                const unsigned short* __restrict__ B,
                unsigned short* __restrict__ C)
{
    constexpr int K = D_REAL, N = D_HID;
    __shared__ __align__(16) unsigned short As[64 * 32];    // 4 KB
    __shared__ __align__(16) unsigned short Bs[128 * 32];   // 8 KB
    __shared__ int sIds[64];

    const int tid = threadIdx.x;
    const int rowBase = blockIdx.x * 64;
    const int colBase = blockIdx.y * 128;

    if (tid < 64) sIds[tid] = ids[rowBase + tid];
    __syncthreads();

    const int srow = tid >> 2;           // 0..63
    const int scol = (tid & 3) * 8;      // k offset
    const float* gA = real + (size_t)sIds[srow] * K + scol;
    const unsigned short* gB = B + (size_t)(colBase + srow) * K + scol;
    unsigned short* lB = Bs + (tid >> 6) * 512;

    const int lane = tid & 63;
    const int wv   = tid >> 6;
    const int wm   = (wv >> 1) * 32;
    const int wn   = (wv & 1) * 64;
    const int frow = lane & 15;
    const int fk   = (lane >> 4) * 8;

    f32x4 acc[2][4];
    #pragma unroll
    for (int i = 0; i < 2; i++)
        #pragma unroll
        for (int j = 0; j < 4; j++) acc[i][j] = (f32x4)0.f;

    for (int k0 = 0; k0 < K; k0 += 32) {
        gload_lds16(gB + k0,                lB);
        gload_lds16(gB + k0 + (size_t)64*K, lB + 2048);
        const float4 a0 = *reinterpret_cast<const float4*>(gA + k0);
        const float4 a1 = *reinterpret_cast<const float4*>(gA + k0 + 4);
        *reinterpret_cast<bf16x8*>(&As[srow * 32 + scol]) = cvt8(a0, a1);
        __syncthreads();   // drains gloads + ds_write + a-loads

        bf16x8 af[2], bg[4];
        #pragma unroll
        for (int i = 0; i < 2; i++)
            af[i] = *reinterpret_cast<const bf16x8*>(&As[(wm + i*16 + frow) * 32 + fk]);
        #pragma unroll
        for (int j = 0; j < 4; j++)
            bg[j] = *reinterpret_cast<const bf16x8*>(&Bs[(wn + j*16 + frow) * 32 + fk]);

        #pragma unroll
        for (int i = 0; i < 2; i++)
            #pragma unroll
            for (int j = 0; j < 4; j++)
                acc[i][j] = __builtin_amdgcn_mfma_f32_16x16x32_bf16(af[i], bg[j], acc[i][j], 0, 0, 0);
        __syncthreads();
    }

    const int orow0 = wm + (lane >> 4) * 4;
    const int ocol0 = wn + frow;
    #pragma unroll
    for (int i = 0; i < 2; i++)
        #pragma unroll
        for (int r = 0; r < 4; r++) {
            unsigned short* dst = C + (size_t)(rowBase + orow0 + i*16 + r) * N + colBase + ocol0;
            #pragma unroll
            for (int j = 0; j < 4; j++)
                dst[j * 16] = f2bf(acc[i][j][r]);
        }
}

// ---------------------------------------------------------------------------
// GEMM2, 8-phase 256x256 schedule (round-8 form, verbatim — best measured):
//   out[8192][4096] = Hb * w2b^T + embed[ids], fp32 out.
// BM=BN=256, BK=64, 512 thr = 8 waves (2Mx4N), per-wave 128x64 = 8x4 frags.
// LDS 128 KB: A[2buf][2half][128][64] bf16 + B same. Both-sides XOR swizzle.
// Counted vmcnt(2) at K-tile boundaries; vmcnt(0) only at tail.
// ---------------------------------------------------------------------------
__global__ __launch_bounds__(512, 2)
void gemm2_8phase(const unsigned short* __restrict__ A,
                  const unsigned short* __restrict__ B,
                  const int* __restrict__ ids,
                  const float* __restrict__ embed,
                  float* __restrict__ C)
{
    constexpr int K = D_HID, N = D_MODEL, NKT = K / 64;   // 8 K-tiles
    __shared__ __align__(16) unsigned short lds[65536];   // 128 KiB
    __shared__ int sIds[256];
    unsigned short* Alds = lds;            // [2buf][2half][128][64]
    unsigned short* Blds = lds + 32768;

    // bijective XCD-slab swizzle over 512 blocks (32 row-tiles x 16 col-tiles)
    const int f   = blockIdx.x;
    const int xcd = f & 7;
    const int idx = f >> 3;                         // 0..63
    const int rowBase = (xcd * 4 + (idx & 3)) * 256;
    const int colBase = (idx >> 2) * 256;

    const int tid  = threadIdx.x;
    const int lane = tid & 63;
    const int wv   = tid >> 6;     // 0..7
    const int wr   = wv >> 2;      // 0..1  (M half)
    const int wc   = wv & 3;       // 0..3  (N quarter)
    const int frow = lane & 15;
    const int fq   = lane >> 4;    // 0..3

    if (tid < 256) sIds[tid] = ids[rowBase + tid];

    // stage half h (128 rows x 64 k) of K-tile kt of matrix M -> buf kt&1
    auto STAGE_HALF = [&](const unsigned short* Mp, unsigned short* Ml,
                          int tileBase, int kt, int h) {
        const int buf = kt & 1;
        #pragma unroll
        for (int u = 0; u < 2; ++u) {
            const int c    = u * 512 + tid;          // chunk 0..1023
            const int row  = c >> 3;                 // 0..127
            const int slot = (c & 7) ^ (row & 7);    // inverse swizzle on source
            const unsigned short* g = Mp + (size_t)(tileBase + h * 128 + row) * K
                                         + kt * 64 + slot * 8;
            unsigned short* l = Ml + (buf * 2 + h) * 8192 + (u * 512 + wv * 64) * 8;
            gload_lds16(g, l);
        }
    };
    auto STAGE = [&](int kt_s, int h_s) {
        if (kt_s >= NKT) return;
        if (h_s < 2) STAGE_HALF(A, Alds, rowBase, kt_s, h_s);
        else         STAGE_HALF(B, Blds, colBase, kt_s, h_s - 2);
    };
    auto LDA = [&](int buf, int mf, int kk) -> bf16x8 {
        const int row  = mf * 16 + frow;             // within half wr
        const int slot = (kk * 4 + fq) ^ (row & 7);
        return *reinterpret_cast<const bf16x8*>(
            Alds + (buf * 2 + wr) * 8192 + row * 64 + slot * 8);
    };
    auto LDB = [&](int buf, int nf, int kk) -> bf16x8 {
        const int rb   = wc * 64 + nf * 16 + frow;   // 0..255
        const int row  = rb & 127;
        const int slot = (kk * 4 + fq) ^ (row & 7);
        return *reinterpret_cast<const bf16x8*>(
            Blds + (buf * 2 + (rb >> 7)) * 8192 + row * 64 + slot * 8);
    };

    f32x4 acc[8][4];
    #pragma unroll
    for (int i = 0; i < 8; i++)
        #pragma unroll
        for (int j = 0; j < 4; j++) acc[i][j] = (f32x4)0.f;

    // prologue: all 4 halves of kt0 + A-half0 of kt1; allow kt1's A0 in flight
    STAGE(0, 0); STAGE(0, 1); STAGE(0, 2); STAGE(0, 3); STAGE(1, 0);
    asm volatile("s_waitcnt vmcnt(2)" ::: "memory");
    __builtin_amdgcn_s_barrier();
    asm volatile("" ::: "memory");

    #pragma unroll
    for (int kt = 0; kt < NKT; ++kt) {
        const int buf = kt & 1;
        bf16x8 bg[4][2];
        #pragma unroll
        for (int p = 0; p < 4; ++p) {
            bf16x8 af[2][2];
            #pragma unroll
            for (int i = 0; i < 2; ++i)
                #pragma unroll
                for (int kk = 0; kk < 2; ++kk)
                    af[i][kk] = LDA(buf, p * 2 + i, kk);
            if (p == 0) {
                #pragma unroll
                for (int nf = 0; nf < 4; ++nf)
                    #pragma unroll
                    for (int kk = 0; kk < 2; ++kk)
                        bg[nf][kk] = LDB(buf, nf, kk);
            }
            if (p < 3) STAGE(kt + 1, p + 1);   // targets buf^1: race-free
            BAR();
            if (p == 3) STAGE(kt + 2, 0);      // targets buf A-half0: issued after
                                               // its last reads crossed the barrier
            __builtin_amdgcn_s_setprio(1);
            #pragma unroll
            for (int i = 0; i < 2; ++i)
                #pragma unroll
                for (int nf = 0; nf < 4; ++nf)
                    #pragma unroll
                    for (int kk = 0; kk < 2; ++kk)
                        acc[p*2+i][nf] = __builtin_amdgcn_mfma_f32_16x16x32_bf16(
                            af[i][kk], bg[nf][kk], acc[p*2+i][nf], 0, 0, 0);
            __builtin_amdgcn_s_setprio(0);
            if (p == 3) {                      // K-tile boundary: counted drain
                if (kt + 2 < NKT)      asm volatile("s_waitcnt vmcnt(2)" ::: "memory");
                else if (kt + 1 < NKT) asm volatile("s_waitcnt vmcnt(0)" ::: "memory");
            }
            BAR();
        }
    }

    // epilogue: scalar fp32 stores + embed gather-add (C/D: row=fq*4+r, col=frow)
    const int ocol0 = colBase + wc * 64 + frow;
    #pragma unroll
    for (int mf = 0; mf < 8; ++mf) {
        #pragma unroll
        for (int r = 0; r < 4; ++r) {
            const int lrow = wr * 128 + mf * 16 + fq * 4 + r;
            const float* e = embed + (size_t)sIds[lrow] * N + ocol0;
            float* o = C + (size_t)(rowBase + lrow) * N + ocol0;
            #pragma unroll
            for (int nf = 0; nf < 4; ++nf)
                o[nf * 16] = acc[mf][nf][r] + e[nf * 16];
        }
    }
}

// ---------------------------------------------------------------------------
// fp32 -> bf16 bulk convert of w1 and w2 in one launch
// ---------------------------------------------------------------------------
__global__ __launch_bounds__(256)
void convert2_bf16(const float* __restrict__ s1, unsigned short* __restrict__ d1, int n1,
                   const float* __restrict__ s2, unsigned short* __restrict__ d2, int n2)
{
    int i = blockIdx.x * 256 + threadIdx.x;
    const float* src; unsigned short* dst;
    if (i < n1) { src = s1; dst = d1; }
    else {
        i -= n1;
        if (i >= n2) return;
        src = s2; dst = d2;
    }
    const float4 v = reinterpret_cast<const float4*>(src)[i];
    ushort4 o;
    o.x = f2bf(v.x); o.y = f2bf(v.y); o.z = f2bf(v.z); o.w = f2bf(v.w);
    reinterpret_cast<ushort4*>(dst)[i] = o;
}

// ---------------------------------------------------------------------------
// In-place LayerNorm + ELU on bf16 H [TOKENS][512]. One wave per row.
// ---------------------------------------------------------------------------
__global__ __launch_bounds__(256)
void ln_elu_bf16(unsigned short* __restrict__ H,
                 const float* __restrict__ ln_w, const float* __restrict__ ln_b)
{
    const int row = blockIdx.x * 4 + (threadIdx.x >> 6);
    const int t = threadIdx.x & 63;
    unsigned short* x = H + (size_t)row * D_HID + t * 8;

    bf16x8 v = *reinterpret_cast<const bf16x8*>(x);
    float fv[8], s = 0.f, ss = 0.f;
    #pragma unroll
    for (int j = 0; j < 8; j++) {
        fv[j] = bf2f((unsigned short)v[j]);
        s += fv[j]; ss += fv[j] * fv[j];
    }
    #pragma unroll
    for (int off = 32; off > 0; off >>= 1) {
        s  += __shfl_down(s, off);
        ss += __shfl_down(ss, off);
    }
    s = __shfl(s, 0); ss = __shfl(ss, 0);
    const float mu = s * (1.f / D_HID);
    const float var = ss * (1.f / D_HID) - mu * mu;
    const float rstd = rsqrtf(var + 1e-5f);

    const float4 w0 = *reinterpret_cast<const float4*>(ln_w + t * 8);
    const float4 w1 = *reinterpret_cast<const float4*>(ln_w + t * 8 + 4);
    const float4 b0 = *reinterpret_cast<const float4*>(ln_b + t * 8);
    const float4 b1 = *reinterpret_cast<const float4*>(ln_b + t * 8 + 4);
    const float wa[8] = { w0.x, w0.y, w0.z, w0.w, w1.x, w1.y, w1.z, w1.w };
    const float ba[8] = { b0.x, b0.y, b0.z, b0.w, b1.x, b1.y, b1.z, b1.w };

    bf16x8 o;
    #pragma unroll
    for (int j = 0; j < 8; j++) {
        float y = (fv[j] - mu) * rstd * wa[j] + ba[j];
        y = y > 0.f ? y : expm1f(y);
        o[j] = (short)f2bf(y);
    }
    *reinterpret_cast<bf16x8*>(x) = o;
}

extern "C" void kernel_launch(void* const* d_in, const int* in_sizes, int n_in,
                              void* d_out, int out_size, void* d_ws, size_t ws_size,
                              hipStream_t stream)
{
    const float* real  = (const float*)d_in[0];   // [32000, 768]
    const float* embed = (const float*)d_in[1];   // [32000, 4096]
    const float* w1    = (const float*)d_in[2];   // [512, 768]
    const float* w2    = (const float*)d_in[3];   // [4096, 512]
    const float* ln_w  = (const float*)d_in[4];   // [512]
    const float* ln_b  = (const float*)d_in[5];   // [512]
    const int*   ids   = (const int*)d_in[6];     // [8192]
    float* out = (float*)d_out;                   // [8192, 4096] fp32

    unsigned short* Hb  = (unsigned short*)d_ws;             // [8192][512] bf16
    unsigned short* w1b = Hb  + (size_t)TOKENS * D_HID;      // [512][768]  bf16
    unsigned short* w2b = w1b + (size_t)D_HID * D_REAL;      // [4096][512] bf16

    const int n1 = D_HID * D_REAL / 4, n2 = D_MODEL * D_HID / 4;
    convert2_bf16<<<(n1 + n2 + 255) / 256, 256, 0, stream>>>(w1, w1b, n1, w2, w2b, n2);

    dim3 g1(TOKENS / 64, D_HID / 128);
    gemm1_mfma<<<g1, 256, 0, stream>>>(real, ids, w1b, Hb);

    ln_elu_bf16<<<TOKENS / 4, 256, 0, stream>>>(Hb, ln_w, ln_b);

    gemm2_8phase<<<512, 512, 0, stream>>>(Hb, w2b, ids, embed, out);
}